// Round 11
// baseline (2783.680 us; speedup 1.0000x reference)
//
#include <hip/hip_runtime.h>
#include <hip/hip_bf16.h>

#define NLVL 20
#define PN   5000
#define EPLE 40000
#define FDIM 128
#define HDIM 256
#define NTOT (NLVL * PN)
#define CAP  32
#define RPW  32                       // rows per wave (= per block)
#define NBLK ((PN + RPW - 1) / RPW)   // 157 blocks, 1 wave each

#define STR_(x) #x
#define GLD(dst, ptr, IMM) \
  asm volatile("global_load_dwordx4 %0, %1, off offset:" STR_(IMM) : "=v"(dst) : "v"(ptr))
#define WAITVM(N) do { asm volatile("s_waitcnt vmcnt(" STR_(N) ")" ::: "memory"); \
                       __builtin_amdgcn_sched_barrier(0); } while (0)

typedef __attribute__((ext_vector_type(8))) short short8;
typedef __attribute__((ext_vector_type(4))) float f32x4;

__device__ __forceinline__ f32x4 mfma16(short8 a, short8 b, f32x4 c) {
  return __builtin_amdgcn_mfma_f32_16x16x32_bf16(a, b, c, 0, 0, 0);
}
__device__ __forceinline__ ushort f2b(float f) {
  union { float f; unsigned u; } v; v.f = f;
  unsigned r = v.u + 0x7FFFu + ((v.u >> 16) & 1u);
  return (ushort)(r >> 16);
}
__device__ __forceinline__ uint2 packu2(f32x4 v) {
  union { uint2 u2; ushort s[4]; } p;
  p.s[0] = f2b(v[0]); p.s[1] = f2b(v[1]); p.s[2] = f2b(v[2]); p.s[3] = f2b(v[3]);
  return p.u2;
}
__device__ __forceinline__ void addbf4(f32x4& s, uint2 v) {
  s[0] += __uint_as_float(v.x << 16);
  s[1] += __uint_as_float(v.x & 0xFFFF0000u);
  s[2] += __uint_as_float(v.y << 16);
  s[3] += __uint_as_float(v.y & 0xFFFF0000u);
}
__device__ __forceinline__ f32x4 relu4(f32x4 a) {
  f32x4 o;
  o[0] = fmaxf(a[0], 0.f); o[1] = fmaxf(a[1], 0.f);
  o[2] = fmaxf(a[2], 0.f); o[3] = fmaxf(a[3], 0.f);
  return o;
}
__device__ __forceinline__ float ftanh(float x) {
  float e = __expf(2.f * x);
  return 1.f - 2.f * __builtin_amdgcn_rcpf(e + 1.f);
}

// ---- wave-private LDS act buffers [32 rows][256 cols] bf16, XOR-swizzled ----
__device__ __forceinline__ void st_lds8(ushort* buf, int row, int off, uint2 v) {
  *(uint2*)((char*)buf + row * 512 + (off ^ ((row & 7) << 4))) = v;
}
__device__ __forceinline__ short8 ld_lds16(const ushort* buf, int row, int off) {
  return *(const short8*)((const char*)buf + row * 512 + (off ^ ((row & 7) << 4)));
}

// group issuers: 8 frags -> ring slot
__device__ __forceinline__ void ldg8(const ushort* p, short8* Wg) {
  GLD(Wg[0], p, 0);   GLD(Wg[1], p, 64);  GLD(Wg[2], p, 128); GLD(Wg[3], p, 192);
  GLD(Wg[4], p, 256); GLD(Wg[5], p, 320); GLD(Wg[6], p, 384); GLD(Wg[7], p, 448);
}
__device__ __forceinline__ void ldg44(const ushort* pa, short8* Wg) {  // embed: 2ct x 4kc
  const ushort* pb = pa + 2048;
  GLD(Wg[0], pa, 0); GLD(Wg[1], pa, 64); GLD(Wg[2], pa, 128); GLD(Wg[3], pa, 192);
  GLD(Wg[4], pb, 0); GLD(Wg[5], pb, 64); GLD(Wg[6], pb, 128); GLD(Wg[7], pb, 192);
}

__device__ __forceinline__ void rdB2(const ushort* buf, short8 (&B)[2][8], int r, int g) {
  #pragma unroll
  for (int rg = 0; rg < 2; ++rg)
    #pragma unroll
    for (int kc = 0; kc < 8; ++kc)
      B[rg][kc] = ld_lds16(buf, rg * 16 + r, 64 * kc + 16 * g);
}
__device__ __forceinline__ void initb(f32x4 (&acc)[16][2], const float* bias_s, int slot, int g) {
  #pragma unroll
  for (int ct = 0; ct < 16; ++ct) {
    f32x4 b = *(const f32x4*)(bias_s + slot * 256 + 16 * ct + 4 * g);
    acc[ct][0] = b; acc[ct][1] = b;
  }
}

// consume 16 groups (8 pairs) of one K=256-plane; continuous cross-stage issue:
// pairs 0..5 issue own groups 4..15, pairs 6,7 issue next plane's groups 0..3.
__device__ __forceinline__ void pairs16(short8 (&W)[32], f32x4 (&acc)[16][2],
                                        const short8 (&B)[2][8],
                                        const ushort* lb, int cts,
                                        const ushort* nlb, int ncts) {
  #pragma unroll
  for (int p = 0; p < 8; ++p) {
    WAITVM(16);
    #pragma unroll
    for (int kc = 0; kc < 8; ++kc) {
      const int s0 = (2 * p) & 3, s1 = (2 * p + 1) & 3;
      acc[2 * p][0]     = mfma16(W[s0 * 8 + kc], B[0][kc], acc[2 * p][0]);
      acc[2 * p][1]     = mfma16(W[s0 * 8 + kc], B[1][kc], acc[2 * p][1]);
      acc[2 * p + 1][0] = mfma16(W[s1 * 8 + kc], B[0][kc], acc[2 * p + 1][0]);
      acc[2 * p + 1][1] = mfma16(W[s1 * 8 + kc], B[1][kc], acc[2 * p + 1][1]);
    }
    if (p < 6) {
      ldg8(lb + (size_t)(2 * p + 4) * cts, &W[((2 * p) & 3) * 8]);
      ldg8(lb + (size_t)(2 * p + 5) * cts, &W[((2 * p + 1) & 3) * 8]);
    } else {
      const int q = (p - 6) * 2;
      ldg8(nlb + (size_t)q * ncts, &W[((2 * p) & 3) * 8]);
      ldg8(nlb + (size_t)(q + 1) * ncts, &W[((2 * p + 1) & 3) * 8]);
    }
  }
}

// stage epilogue: relu, optional residual-sum from P, optional pure-write to P, write IN
__device__ __forceinline__ void epilogue(f32x4 (&acc)[16][2], ushort* INb, ushort* Pb,
                                         bool sumP, bool wrP, int r, int g) {
  #pragma unroll
  for (int ct = 0; ct < 16; ++ct)
    #pragma unroll
    for (int rg = 0; rg < 2; ++rg) {
      f32x4 v = relu4(acc[ct][rg]);
      const int row = rg * 16 + r, off = 32 * ct + 8 * g;
      f32x4 o = v;
      if (sumP) {
        uint2 w = *(const uint2*)((const char*)Pb + row * 512 + (off ^ ((row & 7) << 4)));
        addbf4(o, w);
      }
      if (wrP) st_lds8(Pb, row, off, packu2(v));
      st_lds8(INb, row, off, packu2(o));
    }
}

// ---------------- CSR-lite build ----------------
__global__ void fill_csr_kernel(const int* __restrict__ esrc, const int* __restrict__ edst,
                                int* __restrict__ counts, int* __restrict__ buckets) {
  int e = blockIdx.x * 256 + threadIdx.x;
  if (e >= (NLVL - 1) * EPLE) return;
  int l = e / EPLE;
  int key = l * PN + edst[e];
  int pos = atomicAdd(&counts[key], 1);
  if (pos < CAP) buckets[(size_t)key * CAP + pos] = esrc[e];
}

// ---------------- weight prep: fp32 [K][N] -> bf16 [N][K] ----------------
__global__ void prep_w(const float* __restrict__ we, const float* __restrict__ mpw,
                       const float* __restrict__ nw0, const float* __restrict__ nww,
                       ushort* __restrict__ wet, ushort* __restrict__ mpt,
                       ushort* __restrict__ ne0t, ushort* __restrict__ nwt) {
  int i = blockIdx.x * 256 + threadIdx.x;
  if (i < 256 * 128) { int n = i >> 7, k = i & 127; wet[i] = f2b(we[k * 256 + n]); }
  if (i < 4 * 65536) { int mi = i >> 16, rr = i & 65535, n = rr >> 8, k = rr & 255;
                       mpt[i] = f2b(mpw[mi * 65536 + k * 256 + n]); }
  if (i < 256 * 512) { int n = i >> 9, k = i & 511; ne0t[i] = f2b(nw0[k * 256 + n]); }
  if (i < 3 * 65536) { int mi = i >> 16, rr = i & 65535, n = rr >> 8, k = rr & 255;
                       nwt[i] = f2b(nww[mi * 65536 + k * 256 + n]); }
}

// -------- embed for level-0 rows (final outputs + ring slab 0) --------
__global__ __launch_bounds__(256, 4) void embed0(
    const float* __restrict__ nf, const ushort* __restrict__ wet,
    const float* __restrict__ be, float* __restrict__ out,
    ushort* __restrict__ eb16) {
  const int w = threadIdx.x >> 6, lane = threadIdx.x & 63;
  const int r = lane & 15, g = lane >> 4;
  const int p = blockIdx.x * 16 + r;
  const int pc = p < PN ? p : PN - 1;

  short8 Bn[4];
  const float* nfr = nf + (size_t)pc * FDIM;
  #pragma unroll
  for (int kc = 0; kc < 4; ++kc) {
    f32x4 a0 = *(const f32x4*)(nfr + kc * 32 + 8 * g);
    f32x4 a1 = *(const f32x4*)(nfr + kc * 32 + 8 * g + 4);
    float t[8];
    t[0]=a0[0]; t[1]=a0[1]; t[2]=a0[2]; t[3]=a0[3];
    t[4]=a1[0]; t[5]=a1[1]; t[6]=a1[2]; t[7]=a1[3];
    short8 o;
    #pragma unroll
    for (int i = 0; i < 8; ++i) o[i] = (short)f2b(t[i]);
    Bn[kc] = o;
  }
  const int ct0 = 4 * w;
  #pragma unroll
  for (int t = 0; t < 4; ++t) {
    const int ct = ct0 + t;
    f32x4 acc = *(const f32x4*)(be + 16 * ct + 4 * g);
    #pragma unroll
    for (int kc = 0; kc < 4; ++kc)
      acc = mfma16(*(const short8*)(wet + (size_t)(16 * ct + r) * FDIM + kc * 32 + 8 * g),
                   Bn[kc], acc);
    f32x4 o;
    o[0]=ftanh(acc[0]); o[1]=ftanh(acc[1]); o[2]=ftanh(acc[2]); o[3]=ftanh(acc[3]);
    if (p < PN) {
      *(f32x4*)(out + (size_t)p * HDIM + 16 * ct + 4 * g) = o;
      *(uint2*)(eb16 + (size_t)p * HDIM + 16 * ct + 4 * g) = packu2(o);
    }
  }
}

// ------- wave-autonomous per-level chain: 1 wave = 32 rows, ZERO barriers -------
__global__ __launch_bounds__(64, 1) void level_wave(
    float* __restrict__ eb, const float* __restrict__ nf,
    const ushort* __restrict__ ebA, ushort* __restrict__ ebW,
    const int* __restrict__ counts, const int* __restrict__ buckets,
    const ushort* __restrict__ wet,
    const ushort* __restrict__ mpt, const ushort* __restrict__ ne0t,
    const ushort* __restrict__ nwt,
    const float* __restrict__ be, const float* __restrict__ mpb,
    const float* __restrict__ neb0, const float* __restrict__ neb, int l) {
  __shared__ ushort IN[RPW * 256], P[RPW * 256], BASE[RPW * 256];
  __shared__ float bias_s[9 * 256];
  const int lane = threadIdx.x & 63;
  const int r = lane & 15, g = lane >> 4;
  const int p0 = blockIdx.x * RPW;
  const int lP = l * PN;

  // bias -> LDS (slots 0..3 mp_b, 4 ne_b0, 5..7 ne_b, 8 be); 64 lanes x f32x4
  *(f32x4*)(bias_s + 0 * 256 + 4 * lane) = *(const f32x4*)(mpb + 4 * lane);
  *(f32x4*)(bias_s + 1 * 256 + 4 * lane) = *(const f32x4*)(mpb + 256 + 4 * lane);
  *(f32x4*)(bias_s + 2 * 256 + 4 * lane) = *(const f32x4*)(mpb + 512 + 4 * lane);
  *(f32x4*)(bias_s + 3 * 256 + 4 * lane) = *(const f32x4*)(mpb + 768 + 4 * lane);
  *(f32x4*)(bias_s + 4 * 256 + 4 * lane) = *(const f32x4*)(neb0 + 4 * lane);
  *(f32x4*)(bias_s + 5 * 256 + 4 * lane) = *(const f32x4*)(neb + 4 * lane);
  *(f32x4*)(bias_s + 6 * 256 + 4 * lane) = *(const f32x4*)(neb + 256 + 4 * lane);
  *(f32x4*)(bias_s + 7 * 256 + 4 * lane) = *(const f32x4*)(neb + 512 + 4 * lane);
  *(f32x4*)(bias_s + 8 * 256 + 4 * lane) = *(const f32x4*)(be + 4 * lane);

  // gather (segment-sum) 32 rows from bf16 ring -> IN; 2 rows interleaved for MLP
  #pragma unroll 1
  for (int row = 0; row < RPW; row += 2) {
    int pA = p0 + row, pB = p0 + row + 1;
    int c0 = pA < PN ? min(counts[lP + pA], CAP) : 0;
    int c1 = pB < PN ? min(counts[lP + pB], CAP) : 0;
    const int* bk0 = buckets + (size_t)(lP + (pA < PN ? pA : 0)) * CAP;
    const int* bk1 = buckets + (size_t)(lP + (pB < PN ? pB : 0)) * CAP;
    f32x4 s0 = {0,0,0,0}, s1 = {0,0,0,0};
    int mx = c0 > c1 ? c0 : c1;
    for (int j = 0; j < mx; ++j) {
      if (j < c0) addbf4(s0, *(const uint2*)(ebA + (size_t)(bk0[j] - lP) * HDIM + 4 * lane));
      if (j < c1) addbf4(s1, *(const uint2*)(ebA + (size_t)(bk1[j] - lP) * HDIM + 4 * lane));
    }
    st_lds8(IN, row, 8 * lane, packu2(s0));
    st_lds8(IN, row + 1, 8 * lane, packu2(s1));
  }

  // nf rows -> embed B fragments (2 row-groups)
  short8 Bn[2][4];
  #pragma unroll
  for (int rg = 0; rg < 2; ++rg) {
    int p = p0 + rg * 16 + r;
    const float* nfr = nf + (size_t)((l + 1) * PN + (p < PN ? p : PN - 1)) * FDIM;
    #pragma unroll
    for (int kc = 0; kc < 4; ++kc) {
      f32x4 a0 = *(const f32x4*)(nfr + kc * 32 + 8 * g);
      f32x4 a1 = *(const f32x4*)(nfr + kc * 32 + 8 * g + 4);
      float t[8];
      t[0]=a0[0]; t[1]=a0[1]; t[2]=a0[2]; t[3]=a0[3];
      t[4]=a1[0]; t[5]=a1[1]; t[6]=a1[2]; t[7]=a1[3];
      short8 o;
      #pragma unroll
      for (int i = 0; i < 8; ++i) o[i] = (short)f2b(t[i]);
      Bn[rg][kc] = o;
    }
  }

  short8 W[32];
  f32x4 acc[16][2];
  short8 Bs_[2][8];

  const ushort* ebase = wet + r * FDIM + 8 * g;            // embed lane base
  const ushort* lb1   = mpt + r * 256 + 8 * g;             // S1 lane base

  // ---- start pipeline: issue embed groups 0..3 (ring full: 32 loads) ----
  __builtin_amdgcn_sched_barrier(0);
  ldg44(ebase,          &W[0]);
  ldg44(ebase + 4096,   &W[8]);
  ldg44(ebase + 8192,   &W[16]);
  ldg44(ebase + 12288,  &W[24]);

  // ---- embed phase: 4 pairs; pairs 2,3 issue S1 groups 0..3 ----
  initb(acc, bias_s, 8, g);
  #pragma unroll
  for (int p = 0; p < 4; ++p) {
    WAITVM(16);
    #pragma unroll
    for (int e = 0; e < 2; ++e) {
      const int ct0 = 4 * p + 2 * e, slot = (2 * p + e) & 3;
      #pragma unroll
      for (int kc = 0; kc < 4; ++kc) {
        acc[ct0][0]     = mfma16(W[slot * 8 + kc],     Bn[0][kc], acc[ct0][0]);
        acc[ct0][1]     = mfma16(W[slot * 8 + kc],     Bn[1][kc], acc[ct0][1]);
        acc[ct0 + 1][0] = mfma16(W[slot * 8 + 4 + kc], Bn[0][kc], acc[ct0 + 1][0]);
        acc[ct0 + 1][1] = mfma16(W[slot * 8 + 4 + kc], Bn[1][kc], acc[ct0 + 1][1]);
      }
    }
    if (p < 2) {
      ldg44(ebase + (size_t)(2 * p + 4) * 4096, &W[((2 * p) & 3) * 8]);
      ldg44(ebase + (size_t)(2 * p + 5) * 4096, &W[((2 * p + 1) & 3) * 8]);
    } else {
      const int q = (p - 2) * 2;
      ldg8(lb1 + (size_t)q * 4096,       &W[((2 * p) & 3) * 8]);
      ldg8(lb1 + (size_t)(q + 1) * 4096, &W[((2 * p + 1) & 3) * 8]);
    }
    // tanh + BASE store for this pair's 4 ct
    #pragma unroll
    for (int ct = 4 * p; ct < 4 * p + 4; ++ct)
      #pragma unroll
      for (int rg = 0; rg < 2; ++rg) {
        f32x4 v = acc[ct][rg], o;
        o[0]=ftanh(v[0]); o[1]=ftanh(v[1]); o[2]=ftanh(v[2]); o[3]=ftanh(v[3]);
        st_lds8(BASE, rg * 16 + r, 32 * ct + 8 * g, packu2(o));
      }
  }

  // ---- S1..S4 (t0, u1, u2, mr) ----
  const ushort* lb = lb1;
  #pragma unroll 1
  for (int s = 0; s < 4; ++s) {
    rdB2(IN, Bs_, r, g);
    initb(acc, bias_s, s, g);
    const ushort* nlb; int ncts;
    if (s < 3) { nlb = mpt + (size_t)(s + 1) * 65536 + r * 256 + 8 * g; ncts = 4096; }
    else       { nlb = ne0t + r * 512 + 8 * g; ncts = 8192; }
    pairs16(W, acc, Bs_, lb, 4096, nlb, ncts);
    epilogue(acc, IN, P, /*sumP*/ (s == 1) || (s == 2), /*wrP*/ (s == 0) || (s == 1), r, g);
    lb = nlb;
  }

  // ---- S5: x0 = relu([base | mr] @ ne_w0 + b) — two K-planes ----
  {
    short8 Bb[2][8];
    rdB2(BASE, Bb, r, g);            // base (k 0..255)
    rdB2(IN, Bs_, r, g);             // mr   (k 256..511)
    initb(acc, bias_s, 4, g);
    const ushort* lb5 = ne0t + r * 512 + 8 * g;
    pairs16(W, acc, Bb,  lb5,       8192, lb5 + 256,            8192);  // plane0 -> plane1
    pairs16(W, acc, Bs_, lb5 + 256, 8192, nwt + r * 256 + 8 * g, 4096); // plane1 -> S6
    epilogue(acc, IN, P, false, true, r, g);      // IN = x0, P = x0
  }

  // ---- S6, S7 (v1, v2) ----
  lb = nwt + r * 256 + 8 * g;
  #pragma unroll 1
  for (int t = 0; t < 2; ++t) {
    rdB2(IN, Bs_, r, g);
    initb(acc, bias_s, 5 + t, g);
    const ushort* nlb = nwt + (size_t)(t + 1) * 65536 + r * 256 + 8 * g;
    pairs16(W, acc, Bs_, lb, 4096, nlb, 4096);
    epilogue(acc, IN, P, true, t == 0, r, g);     // S6: sum x0, keep v1; S7: sum v1
    lb = nlb;
  }

  // ---- S8 (out); "next" issue = dummy reload of wet (keeps vmcnt uniform) ----
  rdB2(IN, Bs_, r, g);
  initb(acc, bias_s, 7, g);
  pairs16(W, acc, Bs_, lb, 4096, ebase, 4096);
  WAITVM(0);
  #pragma unroll
  for (int ct = 0; ct < 16; ++ct)
    #pragma unroll
    for (int rg = 0; rg < 2; ++rg) {
      f32x4 v = relu4(acc[ct][rg]);
      int p = p0 + rg * 16 + r;
      if (p < PN) {
        *(f32x4*)(eb + ((size_t)((l + 1) * PN) + p) * HDIM + 16 * ct + 4 * g) = v;
        *(uint2*)(ebW + (size_t)p * HDIM + 16 * ct + 4 * g) = packu2(v);
      }
    }
}

// ---------------- launch ----------------
extern "C" void kernel_launch(void* const* d_in, const int* in_sizes, int n_in,
                              void* d_out, int out_size, void* d_ws, size_t ws_size,
                              hipStream_t stream) {
  (void)in_sizes; (void)n_in; (void)out_size; (void)ws_size;
  const float* nf      = (const float*)d_in[0];
  const float* W_embed = (const float*)d_in[1];
  const float* b_embed = (const float*)d_in[2];
  const float* mp_w    = (const float*)d_in[3];
  const float* mp_b    = (const float*)d_in[4];
  const float* ne_w0   = (const float*)d_in[5];
  const float* ne_b0   = (const float*)d_in[6];
  const float* ne_w    = (const float*)d_in[7];
  const float* ne_b    = (const float*)d_in[8];
  const int*   esrc    = (const int*)d_in[9];
  const int*   edst    = (const int*)d_in[10];
  float* out = (float*)d_out;

  int*    counts  = (int*)d_ws;
  int*    buckets = (int*)((char*)d_ws + (512 << 10));
  ushort* wet     = (ushort*)((char*)d_ws + (13u << 20));
  ushort* mpt     = wet + 256 * 128;
  ushort* ne0t    = mpt + 4 * 65536;
  ushort* nwt     = ne0t + 256 * 512;
  ushort* eb16    = (ushort*)((char*)d_ws + (16u << 20));   // bf16 ring: 2 x PN x 256

  hipMemsetAsync(counts, 0, (NLVL - 1) * PN * sizeof(int), stream);
  fill_csr_kernel<<<((NLVL - 1) * EPLE + 255) / 256, 256, 0, stream>>>(esrc, edst, counts, buckets);
  prep_w<<<1024, 256, 0, stream>>>(W_embed, mp_w, ne_w0, ne_w, wet, mpt, ne0t, nwt);
  embed0<<<(PN + 15) / 16, 256, 0, stream>>>(nf, wet, b_embed, out, eb16);
  for (int l = 0; l < NLVL - 1; ++l) {
    ushort* ebA = eb16 + (size_t)(l & 1) * PN * HDIM;
    ushort* ebW = eb16 + (size_t)((l + 1) & 1) * PN * HDIM;
    level_wave<<<NBLK, 64, 0, stream>>>(out, nf, ebA, ebW, counts, buckets,
                                        wet, mpt, ne0t, nwt,
                                        b_embed, mp_b, ne_b0, ne_b, l);
  }
}

// Round 12
// 861.024 us; speedup vs baseline: 3.2330x; 3.2330x over previous
//
#include <hip/hip_runtime.h>
#include <hip/hip_bf16.h>

#define NLVL 20
#define PN   5000
#define EPLE 40000
#define FDIM 128
#define HDIM 256
#define NTOT (NLVL * PN)
#define CAP  32
#define ROWS 32

#define STR_(x) #x
#define GLD(dst, ptr, IMM) \
  asm volatile("global_load_dwordx4 %0, %1, off offset:" STR_(IMM) : "=v"(dst) : "v"(ptr))
#define WAITVM(N) do { asm volatile("s_waitcnt vmcnt(" STR_(N) ")" ::: "memory"); \
                       __builtin_amdgcn_sched_barrier(0); } while (0)
#define LBAR() do { asm volatile("s_waitcnt lgkmcnt(0)\n\ts_barrier" ::: "memory"); \
                    __builtin_amdgcn_sched_barrier(0); } while (0)

typedef __attribute__((ext_vector_type(8))) short short8;
typedef __attribute__((ext_vector_type(4))) float f32x4;

__device__ __forceinline__ f32x4 mfma16(short8 a, short8 b, f32x4 c) {
  return __builtin_amdgcn_mfma_f32_16x16x32_bf16(a, b, c, 0, 0, 0);
}
__device__ __forceinline__ ushort f2b(float f) {
  union { float f; unsigned u; } v; v.f = f;
  unsigned r = v.u + 0x7FFFu + ((v.u >> 16) & 1u);   // RNE
  return (ushort)(r >> 16);
}
__device__ __forceinline__ uint2 packu2(f32x4 v) {
  union { uint2 u2; ushort s[4]; } p;
  p.s[0] = f2b(v[0]); p.s[1] = f2b(v[1]); p.s[2] = f2b(v[2]); p.s[3] = f2b(v[3]);
  return p.u2;
}
__device__ __forceinline__ void addbf4(f32x4& s, uint2 v) {
  s[0] += __uint_as_float(v.x << 16);
  s[1] += __uint_as_float(v.x & 0xFFFF0000u);
  s[2] += __uint_as_float(v.y << 16);
  s[3] += __uint_as_float(v.y & 0xFFFF0000u);
}
__device__ __forceinline__ f32x4 relu4(f32x4 a) {
  f32x4 o;
  o[0] = fmaxf(a[0], 0.f); o[1] = fmaxf(a[1], 0.f);
  o[2] = fmaxf(a[2], 0.f); o[3] = fmaxf(a[3], 0.f);
  return o;
}

// ---- LDS act buffers: [32 rows][256 cols] bf16, XOR-swizzled ----
__device__ __forceinline__ void st_lds8(ushort* buf, int row, int byteoff, uint2 v) {
  *(uint2*)((char*)buf + row * 512 + (byteoff ^ ((row & 7) << 4))) = v;
}
__device__ __forceinline__ short8 ld_lds16(const ushort* buf, int row, int byteoff) {
  return *(const short8*)((const char*)buf + row * 512 + (byteoff ^ ((row & 7) << 4)));
}

// ---- fragment-major weights ----
// Each matrix is stored as chunks of 1KB: chunk(ct, kc) = [64 lanes][short8].
// A wave's GLD at (chunkbase + lane*16B) is one contiguous 1KB burst (ideal
// coalescing, one TA request) instead of 16 scattered 64B lines (R7-R11 wall).
// K=256 matrices: 16 ct x 8 kc chunks; ct stride = 8*512 ushorts = 4096.
// ne0 (K=512): 16 ct x 16 kc; ct stride 8192. embed (K=128): 16 ct x 4 kc; 2048.
__device__ __forceinline__ void ldw_asm(const ushort* __restrict__ Wm, int ctstride,
                                        short8* W, int cc0, int lane) {
  const ushort* pa = Wm + (size_t)cc0 * ctstride + lane * 8;
  const ushort* pb = pa + ctstride;
  GLD(W[0],  pa, 0);        GLD(W[1],  pa, 1024);
  GLD(W[2],  pa, 2048);     GLD(W[3],  pa, 3072);
  GLD(W[4],  pa + 2048, 0); GLD(W[5],  pa + 2048, 1024);
  GLD(W[6],  pa + 2048, 2048); GLD(W[7], pa + 2048, 3072);
  GLD(W[8],  pb, 0);        GLD(W[9],  pb, 1024);
  GLD(W[10], pb, 2048);     GLD(W[11], pb, 3072);
  GLD(W[12], pb + 2048, 0); GLD(W[13], pb + 2048, 1024);
  GLD(W[14], pb + 2048, 2048); GLD(W[15], pb + 2048, 3072);
}

__device__ __forceinline__ void rdBh(const ushort* buf, short8 B[2][4], int h, int r, int g) {
  #pragma unroll
  for (int rg = 0; rg < 2; ++rg)
    #pragma unroll
    for (int kc = 0; kc < 4; ++kc)
      B[rg][kc] = ld_lds16(buf, rg * 16 + r, 64 * (h * 4 + kc) + 16 * g);
}
__device__ __forceinline__ void mmhalf(const short8* W, short8 B[2][4],
                                       f32x4 acc[2][2], int h) {
  #pragma unroll
  for (int ct = 0; ct < 2; ++ct)
    #pragma unroll
    for (int rg = 0; rg < 2; ++rg)
      #pragma unroll
      for (int kc = 0; kc < 4; ++kc)
        acc[ct][rg] = mfma16(W[ct * 8 + h * 4 + kc], B[rg][kc], acc[ct][rg]);
}
__device__ __forceinline__ void stage_mm(const short8* W, const ushort* inbuf,
                                         const float* bias_s, int slot,
                                         f32x4 acc[2][2], int r, int g, int cc0) {
  #pragma unroll
  for (int ct = 0; ct < 2; ++ct) {
    f32x4 b = *(const f32x4*)(bias_s + slot * 256 + 16 * (cc0 + ct) + 4 * g);
    acc[ct][0] = b; acc[ct][1] = b;
  }
  short8 B[2][4];
  rdBh(inbuf, B, 0, r, g);
  mmhalf(W, B, acc, 0);
  rdBh(inbuf, B, 1, r, g);
  mmhalf(W, B, acc, 1);
}
__device__ __forceinline__ void relu_acc(f32x4 a[2][2]) {
  #pragma unroll
  for (int ct = 0; ct < 2; ++ct)
    #pragma unroll
    for (int rg = 0; rg < 2; ++rg) a[ct][rg] = relu4(a[ct][rg]);
}
__device__ __forceinline__ void wr_acc(ushort* buf, f32x4 a[2][2], int cc0, int r, int g) {
  #pragma unroll
  for (int ct = 0; ct < 2; ++ct)
    #pragma unroll
    for (int rg = 0; rg < 2; ++rg)
      st_lds8(buf, rg * 16 + r, 32 * (cc0 + ct) + 8 * g, packu2(a[ct][rg]));
}
__device__ __forceinline__ void wr_acc_add(ushort* buf, f32x4 a[2][2], f32x4 x[2][2],
                                           int cc0, int r, int g) {
  #pragma unroll
  for (int ct = 0; ct < 2; ++ct)
    #pragma unroll
    for (int rg = 0; rg < 2; ++rg)
      st_lds8(buf, rg * 16 + r, 32 * (cc0 + ct) + 8 * g, packu2(a[ct][rg] + x[ct][rg]));
}
__device__ __forceinline__ void cp_acc(f32x4 d[2][2], f32x4 s[2][2]) {
  #pragma unroll
  for (int ct = 0; ct < 2; ++ct)
    #pragma unroll
    for (int rg = 0; rg < 2; ++rg) d[ct][rg] = s[ct][rg];
}

// ---------------- CSR-lite build ----------------
__global__ void fill_csr_kernel(const int* __restrict__ esrc, const int* __restrict__ edst,
                                int* __restrict__ counts, int* __restrict__ buckets) {
  int e = blockIdx.x * 256 + threadIdx.x;
  if (e >= (NLVL - 1) * EPLE) return;
  int l = e / EPLE;
  int key = l * PN + edst[e];
  int pos = atomicAdd(&counts[key], 1);
  if (pos < CAP) buckets[(size_t)key * CAP + pos] = esrc[e];
}

// ------- weight prep: fp32 [K][N] row-major -> bf16 fragment-major chunks -------
__global__ void prep_w(const float* __restrict__ we, const float* __restrict__ mpw,
                       const float* __restrict__ nw0, const float* __restrict__ nww,
                       ushort* __restrict__ wef, ushort* __restrict__ mpf,
                       ushort* __restrict__ ne0f, ushort* __restrict__ nwf) {
  int i = blockIdx.x * 256 + threadIdx.x;
  // embed: 16 ct x 4 kc chunks (K=128)
  if (i < 32768) {
    int e = i & 7, lane = (i >> 3) & 63, kc = (i >> 9) & 3, ct = i >> 11;
    int r = lane & 15, g = lane >> 4;
    int k = kc * 32 + 8 * g + e, n = 16 * ct + r;
    wef[i] = f2b(we[k * 256 + n]);
  }
  // mp: 4 matrices, each 16 ct x 8 kc (K=256)
  if (i < 4 * 65536) {
    int mi = i >> 16, o = i & 65535;
    int e = o & 7, lane = (o >> 3) & 63, kc = (o >> 9) & 7, ct = o >> 12;
    int r = lane & 15, g = lane >> 4;
    int k = kc * 32 + 8 * g + e, n = 16 * ct + r;
    mpf[i] = f2b(mpw[mi * 65536 + k * 256 + n]);
  }
  // ne0: 16 ct x 16 kc (K=512)
  if (i < 131072) {
    int e = i & 7, lane = (i >> 3) & 63, kc = (i >> 9) & 15, ct = i >> 13;
    int r = lane & 15, g = lane >> 4;
    int k = kc * 32 + 8 * g + e, n = 16 * ct + r;
    ne0f[i] = f2b(nw0[k * 256 + n]);
  }
  // nw: 3 matrices, 16 ct x 8 kc
  if (i < 3 * 65536) {
    int mi = i >> 16, o = i & 65535;
    int e = o & 7, lane = (o >> 3) & 63, kc = (o >> 9) & 7, ct = o >> 12;
    int r = lane & 15, g = lane >> 4;
    int k = kc * 32 + 8 * g + e, n = 16 * ct + r;
    nwf[i] = f2b(nww[mi * 65536 + k * 256 + n]);
  }
}

// -------- embed for level-0 rows: 16 rows/block, 4 waves x 4 col-tiles --------
__global__ __launch_bounds__(256, 4) void embed0(
    const float* __restrict__ nf, const ushort* __restrict__ wef,
    const float* __restrict__ be, float* __restrict__ out,
    ushort* __restrict__ eb16) {
  const int w = threadIdx.x >> 6, lane = threadIdx.x & 63;
  const int r = lane & 15, g = lane >> 4;
  const int p = blockIdx.x * 16 + r;
  const int pc = p < PN ? p : PN - 1;

  short8 Bn[4];
  const float* nfr = nf + (size_t)pc * FDIM;
  #pragma unroll
  for (int kc = 0; kc < 4; ++kc) {
    f32x4 a0 = *(const f32x4*)(nfr + kc * 32 + 8 * g);
    f32x4 a1 = *(const f32x4*)(nfr + kc * 32 + 8 * g + 4);
    float t[8];
    t[0]=a0[0]; t[1]=a0[1]; t[2]=a0[2]; t[3]=a0[3];
    t[4]=a1[0]; t[5]=a1[1]; t[6]=a1[2]; t[7]=a1[3];
    short8 o;
    #pragma unroll
    for (int i = 0; i < 8; ++i) o[i] = (short)f2b(t[i]);
    Bn[kc] = o;
  }
  const int ct0 = 4 * w;
  #pragma unroll
  for (int t = 0; t < 4; ++t) {
    const int ct = ct0 + t;
    f32x4 acc = *(const f32x4*)(be + 16 * ct + 4 * g);
    #pragma unroll
    for (int kc = 0; kc < 4; ++kc)
      acc = mfma16(*(const short8*)(wef + (size_t)ct * 2048 + kc * 512 + lane * 8),
                   Bn[kc], acc);
    f32x4 o;
    o[0]=tanhf(acc[0]); o[1]=tanhf(acc[1]); o[2]=tanhf(acc[2]); o[3]=tanhf(acc[3]);
    if (p < PN) {
      *(f32x4*)(out + (size_t)p * HDIM + 16 * ct + 4 * g) = o;
      *(uint2*)(eb16 + (size_t)p * HDIM + 16 * ct + 4 * g) = packu2(o);
    }
  }
}

// ------- fused per-level chain: 32 rows/block, 8 waves x (2 ct x 2 rg) -------
// R8 structure verbatim; only the weight addressing is fragment-major.
__global__ __launch_bounds__(512, 2) void level_mfma(
    float* __restrict__ eb, const float* __restrict__ nf,
    const ushort* __restrict__ ebA, ushort* __restrict__ ebW,
    const int* __restrict__ counts, const int* __restrict__ buckets,
    const ushort* __restrict__ wef,
    const ushort* __restrict__ mpf, const ushort* __restrict__ ne0f,
    const ushort* __restrict__ nwf,
    const float* __restrict__ be, const float* __restrict__ mpb,
    const float* __restrict__ neb0, const float* __restrict__ neb, int l) {
  __shared__ ushort Bs[4][ROWS * 256];
  __shared__ float bias_s[8 * 256];
  const int tid = threadIdx.x, w = tid >> 6, lane = tid & 63;
  const int r = lane & 15, g = lane >> 4;
  const int p0 = blockIdx.x * ROWS;
  const int cc0 = 2 * w;
  const int lP = l * PN;

  short8 WA[16], WB[16], WE[8];
  f32x4 acc[2][2], X[2][2];

  // ---- issue embed weights + S1 weights FIRST (land under phase-0 gather) ----
  {
    const ushort* pe0 = wef + (size_t)cc0 * 2048 + lane * 8;
    const ushort* pe1 = pe0 + 2048;
    GLD(WE[0], pe0, 0); GLD(WE[1], pe0, 1024); GLD(WE[2], pe0, 2048); GLD(WE[3], pe0, 3072);
    GLD(WE[4], pe1, 0); GLD(WE[5], pe1, 1024); GLD(WE[6], pe1, 2048); GLD(WE[7], pe1, 3072);
  }
  ldw_asm(mpf, 4096, WA, cc0, lane);                   // S1 weights

  // bias table -> LDS (slots: 0..3 mp_b, 4 ne_b0, 5..7 ne_b)
  for (int i = tid; i < 2048; i += 512) {
    float v;
    if (i < 1024) v = mpb[i];
    else if (i < 1280) v = neb0[i - 1024];
    else v = neb[i - 1280];
    bias_s[i] = v;
  }

  // ---- phase 0: gather (4 rows/wave) from bf16 ring -> Bs0 ----
  {
    const int qb = 4 * w;
    f32x4 s[4]; int cnt[4]; const int* bk[4];
    #pragma unroll
    for (int i = 0; i < 4; ++i) {
      int p = p0 + qb + i;
      int pc = p < PN ? p : PN - 1;
      cnt[i] = p < PN ? min(counts[lP + p], CAP) : 0;
      bk[i] = buckets + (size_t)(lP + pc) * CAP;
      s[i][0]=0.f; s[i][1]=0.f; s[i][2]=0.f; s[i][3]=0.f;
    }
    int mx = max(max(cnt[0], cnt[1]), max(cnt[2], cnt[3]));
    for (int j = 0; j < mx; ++j) {
      #pragma unroll
      for (int i = 0; i < 4; ++i)
        if (j < cnt[i]) {
          int sl = bk[i][j] - lP;
          addbf4(s[i], *(const uint2*)(ebA + (size_t)sl * HDIM + 4 * lane));
        }
    }
    #pragma unroll
    for (int i = 0; i < 4; ++i)
      st_lds8(Bs[0], qb + i, 8 * lane, packu2(s[i]));
  }

  // ---- fused embed: base = tanh(nf @ We + be) -> Bs3 ----
  {
    short8 Bn[2][4];
    #pragma unroll
    for (int rg = 0; rg < 2; ++rg) {
      int p = p0 + rg * 16 + r;
      const float* nfr = nf + (size_t)((l + 1) * PN + (p < PN ? p : PN - 1)) * FDIM;
      #pragma unroll
      for (int kc = 0; kc < 4; ++kc) {
        f32x4 a0 = *(const f32x4*)(nfr + kc * 32 + 8 * g);
        f32x4 a1 = *(const f32x4*)(nfr + kc * 32 + 8 * g + 4);
        float t[8];
        t[0]=a0[0]; t[1]=a0[1]; t[2]=a0[2]; t[3]=a0[3];
        t[4]=a1[0]; t[5]=a1[1]; t[6]=a1[2]; t[7]=a1[3];
        short8 o;
        #pragma unroll
        for (int i = 0; i < 8; ++i) o[i] = (short)f2b(t[i]);
        Bn[rg][kc] = o;
      }
    }
    f32x4 b0 = *(const f32x4*)(be + 16 * cc0 + 4 * g);
    f32x4 b1 = *(const f32x4*)(be + 16 * (cc0 + 1) + 4 * g);
    acc[0][0] = b0; acc[0][1] = b0; acc[1][0] = b1; acc[1][1] = b1;
    WAITVM(0);                                          // WE landed
    #pragma unroll
    for (int ct = 0; ct < 2; ++ct)
      #pragma unroll
      for (int rg = 0; rg < 2; ++rg)
        #pragma unroll
        for (int kc = 0; kc < 4; ++kc)
          acc[ct][rg] = mfma16(WE[ct * 4 + kc], Bn[rg][kc], acc[ct][rg]);
    #pragma unroll
    for (int ct = 0; ct < 2; ++ct)
      #pragma unroll
      for (int rg = 0; rg < 2; ++rg) {
        f32x4 o;
        o[0]=tanhf(acc[ct][rg][0]); o[1]=tanhf(acc[ct][rg][1]);
        o[2]=tanhf(acc[ct][rg][2]); o[3]=tanhf(acc[ct][rg][3]);
        st_lds8(Bs[3], rg * 16 + r, 32 * (cc0 + ct) + 8 * g, packu2(o));
      }
  }
  LBAR();

  // ---- S1: t0 ---- [use WA(mp0); issue WB=mp1]
  ldw_asm(mpf + 65536, 4096, WB, cc0, lane);
  WAITVM(16);
  stage_mm(WA, Bs[0], bias_s, 0, acc, r, g, cc0);
  relu_acc(acc);
  wr_acc(Bs[1], acc, cc0, r, g);
  cp_acc(X, acc);
  LBAR();

  // ---- S2: u1 ---- [use WB(mp1); issue WA=mp2]
  ldw_asm(mpf + 131072, 4096, WA, cc0, lane);
  WAITVM(16);
  stage_mm(WB, Bs[1], bias_s, 1, acc, r, g, cc0);
  relu_acc(acc);
  wr_acc_add(Bs[2], acc, X, cc0, r, g);                 // t0+u1
  cp_acc(X, acc);                                       // keep u1
  LBAR();

  // ---- S3: u2 ---- [use WA(mp2); issue WB=mp3]
  ldw_asm(mpf + 196608, 4096, WB, cc0, lane);
  WAITVM(16);
  stage_mm(WA, Bs[2], bias_s, 2, acc, r, g, cc0);
  relu_acc(acc);
  wr_acc_add(Bs[0], acc, X, cc0, r, g);                 // u1+u2
  LBAR();

  // ---- S4: mr ---- [use WB(mp3); issue WA=ne0 h1 (kc 0..7)]
  ldw_asm(ne0f, 8192, WA, cc0, lane);
  WAITVM(16);
  stage_mm(WB, Bs[0], bias_s, 3, acc, r, g, cc0);
  relu_acc(acc);
  wr_acc(Bs[1], acc, cc0, r, g);                        // mr
  LBAR();

  // ---- S5: x0 = relu([base|mr] @ ne_w0) ---- [h1 in WA; issue h2 -> WB]
  ldw_asm(ne0f + 4096, 8192, WB, cc0, lane);            // h2 (kc 8..15)
  WAITVM(16);                                           // h1 landed
  {
    acc[0][0] = *(const f32x4*)(bias_s + 4 * 256 + 16 * cc0 + 4 * g);
    acc[0][1] = acc[0][0];
    acc[1][0] = *(const f32x4*)(bias_s + 4 * 256 + 16 * (cc0 + 1) + 4 * g);
    acc[1][1] = acc[1][0];
    short8 B[2][4];
    rdBh(Bs[3], B, 0, r, g); mmhalf(WA, B, acc, 0);     // base k 0..127
    rdBh(Bs[3], B, 1, r, g); mmhalf(WA, B, acc, 1);     // base k 128..255
    WAITVM(0);                                          // h2 landed
    rdBh(Bs[1], B, 0, r, g); mmhalf(WB, B, acc, 0);     // mr k 0..127
    rdBh(Bs[1], B, 1, r, g); mmhalf(WB, B, acc, 1);     // mr k 128..255
  }
  ldw_asm(nwf, 4096, WA, cc0, lane);                    // issue S6 (h1 dead)
  relu_acc(acc);
  wr_acc(Bs[2], acc, cc0, r, g);                        // x0
  cp_acc(X, acc);                                       // keep x0
  LBAR();

  // ---- S6: v1 ---- [use WA(nw0); issue WB=nw1]
  ldw_asm(nwf + 65536, 4096, WB, cc0, lane);
  WAITVM(16);
  stage_mm(WA, Bs[2], bias_s, 5, acc, r, g, cc0);
  relu_acc(acc);
  wr_acc_add(Bs[0], acc, X, cc0, r, g);                 // x0+v1
  cp_acc(X, acc);                                       // keep v1
  LBAR();

  // ---- S7: v2 ---- [use WB(nw1); issue WA=nw2]
  ldw_asm(nwf + 131072, 4096, WA, cc0, lane);
  WAITVM(16);
  stage_mm(WB, Bs[0], bias_s, 6, acc, r, g, cc0);
  relu_acc(acc);
  wr_acc_add(Bs[1], acc, X, cc0, r, g);                 // v1+v2
  LBAR();

  // ---- S8: out ---- [use WA(nw2)]
  WAITVM(0);
  stage_mm(WA, Bs[1], bias_s, 7, acc, r, g, cc0);
  relu_acc(acc);
  #pragma unroll
  for (int rg = 0; rg < 2; ++rg) {
    int p = p0 + rg * 16 + r;
    if (p < PN) {
      float* og = eb + ((size_t)((l + 1) * PN) + p) * HDIM;
      *(f32x4*)(og + 16 * cc0 + 4 * g)       = acc[0][rg];
      *(f32x4*)(og + 16 * (cc0 + 1) + 4 * g) = acc[1][rg];
      ushort* oh = ebW + (size_t)p * HDIM;
      *(uint2*)(oh + 16 * cc0 + 4 * g)       = packu2(acc[0][rg]);
      *(uint2*)(oh + 16 * (cc0 + 1) + 4 * g) = packu2(acc[1][rg]);
    }
  }
}

// ---------------- launch ----------------
extern "C" void kernel_launch(void* const* d_in, const int* in_sizes, int n_in,
                              void* d_out, int out_size, void* d_ws, size_t ws_size,
                              hipStream_t stream) {
  (void)in_sizes; (void)n_in; (void)out_size; (void)ws_size;
  const float* nf      = (const float*)d_in[0];
  const float* W_embed = (const float*)d_in[1];
  const float* b_embed = (const float*)d_in[2];
  const float* mp_w    = (const float*)d_in[3];
  const float* mp_b    = (const float*)d_in[4];
  const float* ne_w0   = (const float*)d_in[5];
  const float* ne_b0   = (const float*)d_in[6];
  const float* ne_w    = (const float*)d_in[7];
  const float* ne_b    = (const float*)d_in[8];
  const int*   esrc    = (const int*)d_in[9];
  const int*   edst    = (const int*)d_in[10];
  float* out = (float*)d_out;

  int*    counts  = (int*)d_ws;
  int*    buckets = (int*)((char*)d_ws + (512 << 10));
  ushort* wef     = (ushort*)((char*)d_ws + (13u << 20));   // fragment-major weights
  ushort* mpf     = wef + 32768;
  ushort* ne0f    = mpf + 4 * 65536;
  ushort* nwf     = ne0f + 131072;
  ushort* eb16    = (ushort*)((char*)d_ws + (16u << 20));   // bf16 ring: 2 x PN x 256

  hipMemsetAsync(counts, 0, (NLVL - 1) * PN * sizeof(int), stream);
  fill_csr_kernel<<<((NLVL - 1) * EPLE + 255) / 256, 256, 0, stream>>>(esrc, edst, counts, buckets);
  prep_w<<<1024, 256, 0, stream>>>(W_embed, mp_w, ne_w0, ne_w, wef, mpf, ne0f, nwf);
  embed0<<<(PN + 15) / 16, 256, 0, stream>>>(nf, wef, b_embed, out, eb16);
  for (int l = 0; l < NLVL - 1; ++l) {
    ushort* ebA = eb16 + (size_t)(l & 1) * PN * HDIM;
    ushort* ebW = eb16 + (size_t)((l + 1) & 1) * PN * HDIM;
    level_mfma<<<(PN + ROWS - 1) / ROWS, 512, 0, stream>>>(out, nf, ebA, ebW,
                                                           counts, buckets,
                                                           wef, mpf, ne0f, nwf,
                                                           b_embed, mp_b, ne_b0, ne_b, l);
  }
}